// Round 2
// baseline (3038.456 us; speedup 1.0000x reference)
//
#include <hip/hip_runtime.h>

// ---------------------------------------------------------------------------
// FlowMatchingShield: 50-step Euler sampler over a 5-layer MLP.
//   base  = state@W0[0:254]+b0            (once, MFMA K=256 padded)
//   tvec[s] = temb(s)@W0[256:320]         (once)
//   per step: h0 = silu(base+tvec+x.W0x)  (elementwise)
//             3x 1024^3 GEMM+SiLU          (bf16 MFMA, LDS-free deep-prefetch)
//             head W4 + Euler update       (fused tail)
// Round-2 change: GEMM reads MFMA fragments DIRECTLY from global (contiguous
// 16B/lane for A[M][K] + B^T[N][K]); no LDS, no barriers, 8-deep register
// prefetch. base_gemm replaced by the same MFMA path (K=256).
// ---------------------------------------------------------------------------

typedef __bf16 bf16x8 __attribute__((ext_vector_type(8)));
typedef float  f32x4  __attribute__((ext_vector_type(4)));
typedef unsigned short u16;
typedef u16 u16x4 __attribute__((ext_vector_type(4)));

#define H 1024
#define BATCH 1024
#define SDIM 254
#define NSTEP 50
#define DT 0.02f

__device__ __forceinline__ u16 f2bf(float f) {
  unsigned int u = __float_as_uint(f);
  return (u16)((u + 0x7FFFu + ((u >> 16) & 1u)) >> 16);
}

__device__ __forceinline__ float silu(float v) {
  return v / (1.0f + __expf(-v));
}

// --- one-time: W[k][n] fp32 -> WT[n][k] bf16, for W1..W3 (blockIdx.z picks) --
__global__ void transpose_w(const float* __restrict__ A, const float* __restrict__ B,
                            const float* __restrict__ C, u16* __restrict__ TA,
                            u16* __restrict__ TB, u16* __restrict__ TC) {
  const float* W = (blockIdx.z == 0) ? A : (blockIdx.z == 1) ? B : C;
  u16* T = (blockIdx.z == 0) ? TA : (blockIdx.z == 1) ? TB : TC;
  __shared__ float tile[32][33];
  const int n0 = blockIdx.x * 32, k0 = blockIdx.y * 32;
  const int tx = threadIdx.x & 31, ty = threadIdx.x >> 5;  // 32 x 8
#pragma unroll
  for (int i = 0; i < 4; ++i)
    tile[ty + 8 * i][tx] = W[(k0 + ty + 8 * i) * H + n0 + tx];
  __syncthreads();
#pragma unroll
  for (int i = 0; i < 4; ++i)
    T[(size_t)(n0 + ty + 8 * i) * H + k0 + tx] = f2bf(tile[tx][ty + 8 * i]);
}

// --- one-time: W0[k][n] (k<256) -> w0t[n][k] bf16 [1024][256] ----------------
__global__ void transpose_w0(const float* __restrict__ W0, u16* __restrict__ T) {
  __shared__ float tile[32][33];
  const int n0 = blockIdx.x * 32, k0 = blockIdx.y * 32;
  const int tx = threadIdx.x & 31, ty = threadIdx.x >> 5;
#pragma unroll
  for (int i = 0; i < 4; ++i)
    tile[ty + 8 * i][tx] = W0[(k0 + ty + 8 * i) * H + n0 + tx];
  __syncthreads();
#pragma unroll
  for (int i = 0; i < 4; ++i)
    T[(size_t)(n0 + ty + 8 * i) * 256 + k0 + tx] = f2bf(tile[tx][ty + 8 * i]);
}

// --- one-time: state fp32 [1024][254] -> bf16 [1024][256] zero-padded --------
__global__ void prep_state(const float* __restrict__ state, u16* __restrict__ sb) {
  const int row = blockIdx.x, col = threadIdx.x;  // 256 threads
  sb[row * 256 + col] = (col < SDIM) ? f2bf(state[row * SDIM + col]) : (u16)0;
}

// --- one-time: tvec[s][h] = sum_j sin(t fj) W0[256+j][h] + cos(t fj) W0[288+j][h]
__global__ void tvec_kernel(const float* __restrict__ W0, float* __restrict__ tvec) {
  const int s = blockIdx.x;
  const int h = blockIdx.y * 256 + threadIdx.x;
  const float t = (float)s * DT;
  float acc = 0.0f;
#pragma unroll
  for (int j = 0; j < 32; ++j) {
    float fr = __expf((float)j * (-9.210340371976184f / 31.0f));
    float ang = t * fr;
    acc += __sinf(ang) * W0[(256 + j) * H + h] + __cosf(ang) * W0[(288 + j) * H + h];
  }
  tvec[s * H + h] = acc;
}

// --- one-time: h0 for step 0 (bf16) + seed x into d_out ----------------------
__global__ void init_kernel(const float* __restrict__ base, const float* __restrict__ tvec,
                            const float* __restrict__ x0, const float* __restrict__ W0,
                            u16* __restrict__ h0, float* __restrict__ xout) {
  const int b = blockIdx.x, tid = threadIdx.x;
  const float xa = x0[2 * b], xb = x0[2 * b + 1];
  if (tid == 0) { xout[2 * b] = xa; xout[2 * b + 1] = xb; }
  const int n = tid * 4;
  float4 bs = *(const float4*)&base[(size_t)b * H + n];
  float4 tv = *(const float4*)&tvec[n];
  float4 wa = *(const float4*)&W0[254 * H + n];
  float4 wb = *(const float4*)&W0[255 * H + n];
  u16x4 r;
  r[0] = f2bf(silu(bs.x + tv.x + xa * wa.x + xb * wb.x));
  r[1] = f2bf(silu(bs.y + tv.y + xa * wa.y + xb * wb.y));
  r[2] = f2bf(silu(bs.z + tv.z + xa * wa.z + xb * wb.z));
  r[3] = f2bf(silu(bs.w + tv.w + xa * wa.w + xb * wb.w));
  *(u16x4*)&h0[(size_t)b * H + n] = r;
}

// --- main GEMM: out = act(A @ BT^T + bias)
// A bf16 [1024][K] row-major, BT bf16 [1024][K] row-major (pre-transposed).
// Single-wave blocks, 32x32 tile, NO LDS: fragments loaded directly from
// global (contiguous 16B/lane), 8-tile-deep register prefetch, no barriers.
// MODE: 0 = silu->bf16, 1 = silu->fp32, 2 = identity->fp32
template <int KTILES, int MODE>
__global__ __launch_bounds__(64) void gemm_mfma(const u16* __restrict__ A,
                                                const u16* __restrict__ BT,
                                                const float* __restrict__ bias,
                                                void* __restrict__ out) {
  const int tid = threadIdx.x;
  const int lr = tid & 15, quad = tid >> 4;
  // XCD swizzle: same-bm blocks land on the same XCD (blockIdx % 8 == XCD),
  // so the A-stripe + B working set stays inside one XCD's 4 MiB L2.
  const int lin = blockIdx.x + 32 * blockIdx.y;
  const int bm = (lin & 7) | ((lin >> 8) << 3);
  const int bn = (lin >> 3) & 31;
  const int K = KTILES * 32;

  // a0 fragment: lane(quad,lr) holds A[bm*32+lr][kt*32 + quad*8 + 0..7]
  const bf16x8* Ap0 = (const bf16x8*)(A + (size_t)(bm * 32 + lr) * K + quad * 8);
  const bf16x8* Ap1 = (const bf16x8*)(A + (size_t)(bm * 32 + 16 + lr) * K + quad * 8);
  const bf16x8* Bp0 = (const bf16x8*)(BT + (size_t)(bn * 32 + lr) * K + quad * 8);
  const bf16x8* Bp1 = (const bf16x8*)(BT + (size_t)(bn * 32 + 16 + lr) * K + quad * 8);
  // bf16x8 = 16B, so K elements = K/8 bf16x8 strides; kt*32 elems = kt*4 vecs
  f32x4 acc[2][2] = {};
  bf16x8 pa0[8], pa1[8], pb0[8], pb1[8];
#pragma unroll
  for (int d = 0; d < 8 && d < KTILES; ++d) {
    pa0[d] = Ap0[d * 4];
    pa1[d] = Ap1[d * 4];
    pb0[d] = Bp0[d * 4];
    pb1[d] = Bp1[d * 4];
  }
#pragma unroll
  for (int kt = 0; kt < KTILES; ++kt) {
    const int s = kt & 7;
    acc[0][0] = __builtin_amdgcn_mfma_f32_16x16x32_bf16(pa0[s], pb0[s], acc[0][0], 0, 0, 0);
    acc[0][1] = __builtin_amdgcn_mfma_f32_16x16x32_bf16(pa0[s], pb1[s], acc[0][1], 0, 0, 0);
    acc[1][0] = __builtin_amdgcn_mfma_f32_16x16x32_bf16(pa1[s], pb0[s], acc[1][0], 0, 0, 0);
    acc[1][1] = __builtin_amdgcn_mfma_f32_16x16x32_bf16(pa1[s], pb1[s], acc[1][1], 0, 0, 0);
    if (kt + 8 < KTILES) {
      const int off = (kt + 8) * 4;
      pa0[s] = Ap0[off];
      pa1[s] = Ap1[off];
      pb0[s] = Bp0[off];
      pb1[s] = Bp1[off];
    }
  }

#pragma unroll
  for (int mt = 0; mt < 2; ++mt)
#pragma unroll
    for (int nt = 0; nt < 2; ++nt) {
      const int gm = bm * 32 + mt * 16 + quad * 4;
      const int gn = bn * 32 + nt * 16 + lr;
      const float bv = bias[gn];
      f32x4 v = acc[mt][nt];
#pragma unroll
      for (int r = 0; r < 4; ++r) {
        float x = v[r] + bv;
        if (MODE != 2) x = silu(x);
        if (MODE == 0) ((u16*)out)[(size_t)(gm + r) * H + gn] = f2bf(x);
        else           ((float*)out)[(size_t)(gm + r) * H + gn] = x;
      }
    }
}

// --- per-step tail: v = h3@W4+b4 ; x += dt*v ; h0(next) = silu(base+tvec+x.W0x)
__global__ void tail_kernel(const float* __restrict__ h3, const float* __restrict__ W4,
                            const float* __restrict__ b4, float* __restrict__ x,
                            const float* __restrict__ base, const float* __restrict__ tvec,
                            const float* __restrict__ W0, u16* __restrict__ h0, int s) {
  const int b = blockIdx.x, tid = threadIdx.x;
  float s0 = 0.0f, s1 = 0.0f;
  for (int h = tid; h < H; h += 256) {
    float v = h3[(size_t)b * H + h];
    s0 += v * W4[2 * h];
    s1 += v * W4[2 * h + 1];
  }
#pragma unroll
  for (int o = 32; o > 0; o >>= 1) {
    s0 += __shfl_down(s0, o);
    s1 += __shfl_down(s1, o);
  }
  __shared__ float red[8];
  __shared__ float xs[2];
  const int w = tid >> 6;
  if ((tid & 63) == 0) { red[w * 2] = s0; red[w * 2 + 1] = s1; }
  __syncthreads();
  if (tid == 0) {
    float v0 = red[0] + red[2] + red[4] + red[6] + b4[0];
    float v1 = red[1] + red[3] + red[5] + red[7] + b4[1];
    float xa = x[2 * b] + DT * v0;
    float xb = x[2 * b + 1] + DT * v1;
    x[2 * b] = xa; x[2 * b + 1] = xb;
    xs[0] = xa; xs[1] = xb;
  }
  __syncthreads();
  if (s < NSTEP - 1) {
    const float xa = xs[0], xb = xs[1];
    const int n = tid * 4;
    float4 bs = *(const float4*)&base[(size_t)b * H + n];
    float4 tv = *(const float4*)&tvec[(size_t)(s + 1) * H + n];
    float4 wa = *(const float4*)&W0[254 * H + n];
    float4 wb = *(const float4*)&W0[255 * H + n];
    u16x4 r;
    r[0] = f2bf(silu(bs.x + tv.x + xa * wa.x + xb * wb.x));
    r[1] = f2bf(silu(bs.y + tv.y + xa * wa.y + xb * wb.y));
    r[2] = f2bf(silu(bs.z + tv.z + xa * wa.z + xb * wb.z));
    r[3] = f2bf(silu(bs.w + tv.w + xa * wa.w + xb * wb.w));
    *(u16x4*)&h0[(size_t)b * H + n] = r;
  }
}

extern "C" void kernel_launch(void* const* d_in, const int* in_sizes, int n_in,
                              void* d_out, int out_size, void* d_ws, size_t ws_size,
                              hipStream_t stream) {
  const float* state = (const float*)d_in[0];
  const float* x0    = (const float*)d_in[1];
  const float* W0    = (const float*)d_in[2];
  const float* b0    = (const float*)d_in[3];
  const float* W1    = (const float*)d_in[4];
  const float* b1    = (const float*)d_in[5];
  const float* W2    = (const float*)d_in[6];
  const float* b2    = (const float*)d_in[7];
  const float* W3    = (const float*)d_in[8];
  const float* b3    = (const float*)d_in[9];
  const float* W4    = (const float*)d_in[10];
  const float* b4    = (const float*)d_in[11];
  float* xout = (float*)d_out;

  char* ws = (char*)d_ws;
  const size_t MB = 1024 * 1024;
  float* base = (float*)(ws + 0);                    // 4 MiB
  float* h3f  = (float*)(ws + 4 * MB);               // 4 MiB
  float* tvec = (float*)(ws + 8 * MB);               // 200 KiB (reserve 256 KiB)
  u16* w1t = (u16*)(ws + 8 * MB + 256 * 1024);       // 2 MiB each
  u16* w2t = (u16*)(ws + 10 * MB + 256 * 1024);
  u16* w3t = (u16*)(ws + 12 * MB + 256 * 1024);
  u16* hA  = (u16*)(ws + 14 * MB + 256 * 1024);
  u16* hB  = (u16*)(ws + 16 * MB + 256 * 1024);
  u16* hC  = (u16*)(ws + 18 * MB + 256 * 1024);
  u16* w0t = (u16*)(ws + 20 * MB + 256 * 1024);      // 512 KiB [1024][256]
  u16* stb = (u16*)(ws + 21 * MB);                   // 512 KiB [1024][256]

  transpose_w<<<dim3(32, 32, 3), 256, 0, stream>>>(W1, W2, W3, w1t, w2t, w3t);
  transpose_w0<<<dim3(32, 8), 256, 0, stream>>>(W0, w0t);
  prep_state<<<BATCH, 256, 0, stream>>>(state, stb);
  gemm_mfma<8, 2><<<dim3(32, 32), 64, 0, stream>>>(stb, w0t, b0, base);
  tvec_kernel<<<dim3(NSTEP, 4), 256, 0, stream>>>(W0, tvec);
  init_kernel<<<BATCH, 256, 0, stream>>>(base, tvec, x0, W0, hA, xout);

  for (int s = 0; s < NSTEP; ++s) {
    gemm_mfma<32, 0><<<dim3(32, 32), 64, 0, stream>>>(hA, w1t, b1, hB);
    gemm_mfma<32, 0><<<dim3(32, 32), 64, 0, stream>>>(hB, w2t, b2, hC);
    gemm_mfma<32, 1><<<dim3(32, 32), 64, 0, stream>>>(hC, w3t, b3, h3f);
    tail_kernel<<<BATCH, 256, 0, stream>>>(h3f, W4, b4, xout, base, tvec, W0, hA, s);
  }
}

// Round 3
// 2328.579 us; speedup vs baseline: 1.3049x; 1.3049x over previous
//
#include <hip/hip_runtime.h>

// ---------------------------------------------------------------------------
// FlowMatchingShield: 50-step Euler sampler over a 5-layer MLP.
//   base  = state@W0[0:254]+b0            (once, MFMA K=256 padded)
//   tvec[s] = temb(s)@W0[256:320]         (once)
//   per step: h0 = silu(base+tvec+x.W0x)  (fused into tail)
//             3x 1024^3 GEMM+SiLU          (bf16 MFMA, 64x64 tile, LDS dbuf)
//             head W4 fused into GEMM3 (atomicAdd) + tiny tail
// Round-3: 64x64 tiles / 256 thr / global_load_lds(16B) double-buffer with a
// single post-compute barrier per K-tile (drain residual only). Round-2's
// indexed prefetch arrays spilled to scratch (VGPR=48 in profile) - no arrays.
// ---------------------------------------------------------------------------

typedef __bf16 bf16x8 __attribute__((ext_vector_type(8)));
typedef float  f32x4  __attribute__((ext_vector_type(4)));
typedef unsigned short u16;
typedef u16 u16x4 __attribute__((ext_vector_type(4)));

#define H 1024
#define BATCH 1024
#define SDIM 254
#define NSTEP 50
#define DT 0.02f

__device__ __forceinline__ u16 f2bf(float f) {
  unsigned int u = __float_as_uint(f);
  return (u16)((u + 0x7FFFu + ((u >> 16) & 1u)) >> 16);
}

__device__ __forceinline__ float silu(float v) {
  return v / (1.0f + __expf(-v));
}

typedef __attribute__((address_space(3))) void lds_void;
typedef __attribute__((address_space(1))) void g_void;
__device__ __forceinline__ void cp16(const void* g, void* l) {
  __builtin_amdgcn_global_load_lds((const g_void*)(uintptr_t)g,
                                   (lds_void*)(uintptr_t)l, 16, 0, 0);
}

// --- one-time: W[k][n] fp32 -> WT[n][k] bf16, for W1..W3 (blockIdx.z picks) --
__global__ void transpose_w(const float* __restrict__ A, const float* __restrict__ B,
                            const float* __restrict__ C, u16* __restrict__ TA,
                            u16* __restrict__ TB, u16* __restrict__ TC) {
  const float* W = (blockIdx.z == 0) ? A : (blockIdx.z == 1) ? B : C;
  u16* T = (blockIdx.z == 0) ? TA : (blockIdx.z == 1) ? TB : TC;
  __shared__ float tile[32][33];
  const int n0 = blockIdx.x * 32, k0 = blockIdx.y * 32;
  const int tx = threadIdx.x & 31, ty = threadIdx.x >> 5;  // 32 x 8
#pragma unroll
  for (int i = 0; i < 4; ++i)
    tile[ty + 8 * i][tx] = W[(k0 + ty + 8 * i) * H + n0 + tx];
  __syncthreads();
#pragma unroll
  for (int i = 0; i < 4; ++i)
    T[(size_t)(n0 + ty + 8 * i) * H + k0 + tx] = f2bf(tile[tx][ty + 8 * i]);
}

// --- one-time: W0[k][n] (k<256) -> w0t[n][k] bf16 [1024][256] ----------------
__global__ void transpose_w0(const float* __restrict__ W0, u16* __restrict__ T) {
  __shared__ float tile[32][33];
  const int n0 = blockIdx.x * 32, k0 = blockIdx.y * 32;
  const int tx = threadIdx.x & 31, ty = threadIdx.x >> 5;
#pragma unroll
  for (int i = 0; i < 4; ++i)
    tile[ty + 8 * i][tx] = W0[(k0 + ty + 8 * i) * H + n0 + tx];
  __syncthreads();
#pragma unroll
  for (int i = 0; i < 4; ++i)
    T[(size_t)(n0 + ty + 8 * i) * 256 + k0 + tx] = f2bf(tile[tx][ty + 8 * i]);
}

// --- one-time: state fp32 [1024][254] -> bf16 [1024][256] zero-padded --------
__global__ void prep_state(const float* __restrict__ state, u16* __restrict__ sb) {
  const int row = blockIdx.x, col = threadIdx.x;  // 256 threads
  sb[row * 256 + col] = (col < SDIM) ? f2bf(state[row * SDIM + col]) : (u16)0;
}

// --- one-time: tvec[s][h] = sum_j sin(t fj) W0[256+j][h] + cos(t fj) W0[288+j][h]
__global__ void tvec_kernel(const float* __restrict__ W0, float* __restrict__ tvec) {
  const int s = blockIdx.x;
  const int h = blockIdx.y * 256 + threadIdx.x;
  const float t = (float)s * DT;
  float acc = 0.0f;
#pragma unroll
  for (int j = 0; j < 32; ++j) {
    float fr = __expf((float)j * (-9.210340371976184f / 31.0f));
    float ang = t * fr;
    acc += __sinf(ang) * W0[(256 + j) * H + h] + __cosf(ang) * W0[(288 + j) * H + h];
  }
  tvec[s * H + h] = acc;
}

// --- one-time: h0 for step 0 (bf16) + seed x into d_out + zero v -------------
__global__ void init_kernel(const float* __restrict__ base, const float* __restrict__ tvec,
                            const float* __restrict__ x0, const float* __restrict__ W0,
                            u16* __restrict__ h0, float* __restrict__ xout,
                            float* __restrict__ v) {
  const int b = blockIdx.x, tid = threadIdx.x;
  const float xa = x0[2 * b], xb = x0[2 * b + 1];
  if (tid == 0) { xout[2 * b] = xa; xout[2 * b + 1] = xb; }
  if (tid < 2) v[2 * b + tid] = 0.0f;
  const int n = tid * 4;
  float4 bs = *(const float4*)&base[(size_t)b * H + n];
  float4 tv = *(const float4*)&tvec[n];
  float4 wa = *(const float4*)&W0[254 * H + n];
  float4 wb = *(const float4*)&W0[255 * H + n];
  u16x4 r;
  r[0] = f2bf(silu(bs.x + tv.x + xa * wa.x + xb * wb.x));
  r[1] = f2bf(silu(bs.y + tv.y + xa * wa.y + xb * wb.y));
  r[2] = f2bf(silu(bs.z + tv.z + xa * wa.z + xb * wb.z));
  r[3] = f2bf(silu(bs.w + tv.w + xa * wa.w + xb * wb.w));
  *(u16x4*)&h0[(size_t)b * H + n] = r;
}

// --- main GEMM: 64x64 block tile, 4 waves (each 32x32), dbuf LDS via
// global_load_lds(16B). A bf16 [1024][K], BT bf16 [1024][K] pre-transposed.
// MODE 0: silu->bf16 store. MODE 2: +bias fp32 store (base). MODE 3: silu,
// fuse head: atomicAdd(v[row][0:2], silu(h3) @ W4), no store.
template <int KTILES, int MODE>
__global__ __launch_bounds__(256) void gemm64(const u16* __restrict__ A,
                                              const u16* __restrict__ BT,
                                              const float* __restrict__ bias,
                                              void* __restrict__ out,
                                              const float* __restrict__ W4,
                                              float* __restrict__ v) {
  constexpr int K = KTILES * 32;
  __shared__ u16 As[2][64 * 32];
  __shared__ u16 Bs[2][64 * 32];
  const int t = threadIdx.x;
  const int lin = blockIdx.x;
  // XCD swizzle: xcd = lin&7; bm = xcd*2 + hi -> each XCD sees 2 bm-stripes
  const int bm = ((lin & 7) << 1) | (lin >> 7);
  const int bn = (lin >> 3) & 15;
  const int w = t >> 6, lane = t & 63;
  const int wm = w & 1, wn = w >> 1;
  const int lr = lane & 15, quad = lane >> 4;

  // fill: thread t -> LDS slot t*16B; global row t/4, col-block (t%3)*8
  const u16* ga = A + (size_t)(bm * 64 + (t >> 2)) * K + (t & 3) * 8;
  const u16* gb = BT + (size_t)(bn * 64 + (t >> 2)) * K + (t & 3) * 8;

  // fragment offsets (u16 elems): row_local*32 + quad*8
  const int aoff0 = (wm * 32 + lr) * 32 + quad * 8;
  const int aoff1 = aoff0 + 16 * 32;
  const int boff0 = (wn * 32 + lr) * 32 + quad * 8;
  const int boff1 = boff0 + 16 * 32;

  f32x4 acc[2][2] = {};

  cp16(ga, &As[0][t * 8]);
  cp16(gb, &Bs[0][t * 8]);
  __syncthreads();

#pragma unroll 2
  for (int kt = 0; kt < KTILES; ++kt) {
    const int cb = kt & 1;
    if (kt + 1 < KTILES) {  // fill next buffer; flight overlaps compute below
      cp16(ga + (kt + 1) * 32, &As[cb ^ 1][t * 8]);
      cp16(gb + (kt + 1) * 32, &Bs[cb ^ 1][t * 8]);
    }
    bf16x8 a0 = *(const bf16x8*)&As[cb][aoff0];
    bf16x8 a1 = *(const bf16x8*)&As[cb][aoff1];
    bf16x8 b0 = *(const bf16x8*)&Bs[cb][boff0];
    bf16x8 b1 = *(const bf16x8*)&Bs[cb][boff1];
    acc[0][0] = __builtin_amdgcn_mfma_f32_16x16x32_bf16(a0, b0, acc[0][0], 0, 0, 0);
    acc[0][1] = __builtin_amdgcn_mfma_f32_16x16x32_bf16(a0, b1, acc[0][1], 0, 0, 0);
    acc[1][0] = __builtin_amdgcn_mfma_f32_16x16x32_bf16(a1, b0, acc[1][0], 0, 0, 0);
    acc[1][1] = __builtin_amdgcn_mfma_f32_16x16x32_bf16(a1, b1, acc[1][1], 0, 0, 0);
    __syncthreads();  // drains next-buf fills (residual) + read/overwrite safety
  }

  const int gn0 = bn * 64 + wn * 32 + lr;
  const int gn1 = gn0 + 16;
  const float bb0 = bias[gn0], bb1 = bias[gn1];

  if (MODE == 3) {
    const float w4a0 = W4[2 * gn0], w4b0 = W4[2 * gn0 + 1];
    const float w4a1 = W4[2 * gn1], w4b1 = W4[2 * gn1 + 1];
#pragma unroll
    for (int mt = 0; mt < 2; ++mt)
#pragma unroll
      for (int r = 0; r < 4; ++r) {
        float sa = silu(acc[mt][0][r] + bb0);
        float sb = silu(acc[mt][1][r] + bb1);
        float c0 = sa * w4a0 + sb * w4a1;
        float c1 = sa * w4b0 + sb * w4b1;
        c0 += __shfl_xor(c0, 1); c0 += __shfl_xor(c0, 2);
        c0 += __shfl_xor(c0, 4); c0 += __shfl_xor(c0, 8);
        c1 += __shfl_xor(c1, 1); c1 += __shfl_xor(c1, 2);
        c1 += __shfl_xor(c1, 4); c1 += __shfl_xor(c1, 8);
        if (lr == 0) {
          const int row = bm * 64 + wm * 32 + mt * 16 + quad * 4 + r;
          atomicAdd(&v[2 * row], c0);
          atomicAdd(&v[2 * row + 1], c1);
        }
      }
  } else {
#pragma unroll
    for (int mt = 0; mt < 2; ++mt) {
      const int gm = bm * 64 + wm * 32 + mt * 16 + quad * 4;
#pragma unroll
      for (int r = 0; r < 4; ++r) {
        float x0 = acc[mt][0][r] + bb0;
        float x1 = acc[mt][1][r] + bb1;
        if (MODE == 0) {
          ((u16*)out)[(size_t)(gm + r) * H + gn0] = f2bf(silu(x0));
          ((u16*)out)[(size_t)(gm + r) * H + gn1] = f2bf(silu(x1));
        } else {
          ((float*)out)[(size_t)(gm + r) * H + gn0] = x0;
          ((float*)out)[(size_t)(gm + r) * H + gn1] = x1;
        }
      }
    }
  }
}

// --- per-step tail: x += dt*(v+b4) ; zero v ; h0(next) = silu(base+tvec+x.W0x)
__global__ void tail2_kernel(float* __restrict__ v, const float* __restrict__ b4,
                             float* __restrict__ x, const float* __restrict__ base,
                             const float* __restrict__ tvec, const float* __restrict__ W0,
                             u16* __restrict__ h0, int s) {
  const int b = blockIdx.x, tid = threadIdx.x;
  const float va = v[2 * b], vb = v[2 * b + 1];
  __syncthreads();
  const float xa = x[2 * b] + DT * (va + b4[0]);
  const float xb = x[2 * b + 1] + DT * (vb + b4[1]);
  if (tid == 0) {
    x[2 * b] = xa; x[2 * b + 1] = xb;
    v[2 * b] = 0.0f; v[2 * b + 1] = 0.0f;  // ready for next step's atomics
  }
  if (s < NSTEP - 1) {
    const int n = tid * 4;
    float4 bs = *(const float4*)&base[(size_t)b * H + n];
    float4 tv = *(const float4*)&tvec[(size_t)(s + 1) * H + n];
    float4 wa = *(const float4*)&W0[254 * H + n];
    float4 wb = *(const float4*)&W0[255 * H + n];
    u16x4 r;
    r[0] = f2bf(silu(bs.x + tv.x + xa * wa.x + xb * wb.x));
    r[1] = f2bf(silu(bs.y + tv.y + xa * wa.y + xb * wb.y));
    r[2] = f2bf(silu(bs.z + tv.z + xa * wa.z + xb * wb.z));
    r[3] = f2bf(silu(bs.w + tv.w + xa * wa.w + xb * wb.w));
    *(u16x4*)&h0[(size_t)b * H + n] = r;
  }
}

extern "C" void kernel_launch(void* const* d_in, const int* in_sizes, int n_in,
                              void* d_out, int out_size, void* d_ws, size_t ws_size,
                              hipStream_t stream) {
  const float* state = (const float*)d_in[0];
  const float* x0    = (const float*)d_in[1];
  const float* W0    = (const float*)d_in[2];
  const float* b0    = (const float*)d_in[3];
  const float* W1    = (const float*)d_in[4];
  const float* b1    = (const float*)d_in[5];
  const float* W2    = (const float*)d_in[6];
  const float* b2    = (const float*)d_in[7];
  const float* W3    = (const float*)d_in[8];
  const float* b3    = (const float*)d_in[9];
  const float* W4    = (const float*)d_in[10];
  const float* b4    = (const float*)d_in[11];
  float* xout = (float*)d_out;

  char* ws = (char*)d_ws;
  const size_t MB = 1024 * 1024;
  float* base = (float*)(ws + 0);                 // 4 MiB
  float* tvec = (float*)(ws + 4 * MB);            // 200 KiB (reserve 256 KiB)
  float* v    = (float*)(ws + 4 * MB + 256 * 1024);  // 8 KiB (reserve 768 KiB)
  u16* w1t = (u16*)(ws + 5 * MB);                 // 2 MiB each
  u16* w2t = (u16*)(ws + 7 * MB);
  u16* w3t = (u16*)(ws + 9 * MB);
  u16* hA  = (u16*)(ws + 11 * MB);                // 2 MiB each
  u16* hB  = (u16*)(ws + 13 * MB);
  u16* hC  = (u16*)(ws + 15 * MB);
  u16* w0t = (u16*)(ws + 17 * MB);                // 512 KiB [1024][256]
  u16* stb = (u16*)(ws + 17 * MB + 512 * 1024);   // 512 KiB [1024][256]

  transpose_w<<<dim3(32, 32, 3), 256, 0, stream>>>(W1, W2, W3, w1t, w2t, w3t);
  transpose_w0<<<dim3(32, 8), 256, 0, stream>>>(W0, w0t);
  prep_state<<<BATCH, 256, 0, stream>>>(state, stb);
  gemm64<8, 2><<<256, 256, 0, stream>>>(stb, w0t, b0, base, nullptr, nullptr);
  tvec_kernel<<<dim3(NSTEP, 4), 256, 0, stream>>>(W0, tvec);
  init_kernel<<<BATCH, 256, 0, stream>>>(base, tvec, x0, W0, hA, xout, v);

  for (int s = 0; s < NSTEP; ++s) {
    gemm64<32, 0><<<256, 256, 0, stream>>>(hA, w1t, b1, hB, nullptr, nullptr);
    gemm64<32, 0><<<256, 256, 0, stream>>>(hB, w2t, b2, hC, nullptr, nullptr);
    gemm64<32, 3><<<256, 256, 0, stream>>>(hC, w3t, b3, nullptr, W4, v);
    tail2_kernel<<<BATCH, 256, 0, stream>>>(v, b4, xout, base, tvec, W0, hA, s);
  }
}